// Round 10
// baseline (255.754 us; speedup 1.0000x reference)
//
#include <hip/hip_runtime.h>
#include <hip/hip_fp16.h>

#define NFEAT 128
#define NHID 64
#define MAXB 1024          // max dst buckets (node>>8), supports N<=262144
#define BSHIFT 8
#define BNODES 256
#define PBLK 512           // edge-pass grid (blocks)
#define DBINS 512          // degree bins for counting sort

typedef _Float16 f16x8 __attribute__((ext_vector_type(8)));
typedef float f32x4 __attribute__((ext_vector_type(4)));

// ================= preprocessing =================

__device__ __forceinline__ int edge_idx(const int* __restrict__ ei, int is64,
                                        long long E, long long e, int which) {
    long long pos = which ? (E + e) : e;
    return is64 ? ei[2 * pos] : ei[pos];
}

__device__ __forceinline__ void load8(const int* __restrict__ ei, int is64,
                                      long long E, long long e0, int which,
                                      int (&v)[8]) {
    if (is64) {
        const int* base = ei + 2 * (which ? E + e0 : e0);
        int4 a = *(const int4*)(base + 0);
        int4 b = *(const int4*)(base + 4);
        int4 c = *(const int4*)(base + 8);
        int4 d = *(const int4*)(base + 12);
        v[0] = a.x; v[1] = a.z; v[2] = b.x; v[3] = b.z;
        v[4] = c.x; v[5] = c.z; v[6] = d.x; v[7] = d.z;
    } else {
        const int* base = ei + (which ? E + e0 : e0);
        int4 a = *(const int4*)(base + 0);
        int4 b = *(const int4*)(base + 4);
        v[0] = a.x; v[1] = a.y; v[2] = a.z; v[3] = a.w;
        v[4] = b.x; v[5] = b.y; v[6] = b.z; v[7] = b.w;
    }
}

// per-block int64 detection: odd int32 words of first 4096 words all zero => int64
__device__ __forceinline__ int block_is64(const int* __restrict__ ei, int* smem) {
    if (threadIdx.x == 0) smem[0] = 0;
    __syncthreads();
    int acc = 0;
    for (int i = 1 + 2 * (int)threadIdx.x; i < 4096; i += 512)
        acc |= ei[i];
    atomicOr(&smem[0], acc);
    __syncthreads();
    int r = (smem[0] == 0) ? 1 : 0;
    __syncthreads();
    return r;
}

// pass 1: per-block bucket histogram -> blockhist (no global atomics)
__global__ __launch_bounds__(256) void k_hist(const int* __restrict__ ei, long long E,
                                              long long perblk,
                                              int* __restrict__ blockhist, int NB) {
    __shared__ int smem[1024];
    int is64 = block_is64(ei, smem);
    int* hist = smem;
    for (int i = threadIdx.x; i < NB; i += 256) hist[i] = 0;
    __syncthreads();
    long long lo = (long long)blockIdx.x * perblk;
    long long hi = lo + perblk; if (hi > E) hi = E;
    if (lo < hi) {
        for (long long e0 = lo + (long long)threadIdx.x * 8; e0 + 8 <= hi; e0 += 256 * 8) {
            int d[8];
            load8(ei, is64, E, e0, 1, d);
#pragma unroll
            for (int j = 0; j < 8; ++j)
                atomicAdd(&hist[d[j] >> BSHIFT], 1);
        }
        long long tail = lo + ((hi - lo) & ~7LL);
        for (long long e = tail + threadIdx.x; e < hi; e += 256) {
            int d = edge_idx(ei, is64, E, e, 1);
            atomicAdd(&hist[d >> BSHIFT], 1);
        }
    }
    __syncthreads();
    int* bh = blockhist + (size_t)blockIdx.x * MAXB;
    for (int i = threadIdx.x; i < NB; i += 256) bh[i] = hist[i];
}

// pass 2: block b<NB scans blockhist column b in place -> exclusive per-block
// offsets; total -> gbhist[b]. Blocks b>=NB zero deghist/dcur and convert
// W1/W2 fp32 -> transposed fp16 (w1t[64][128], w2t[128][64]) -- free work
// folded into an existing dispatch.
__global__ __launch_bounds__(256) void k_colscan(int* __restrict__ blockhist,
                                                 int* __restrict__ gbhist,
                                                 int* __restrict__ deghist,
                                                 int* __restrict__ dcur, int NB,
                                                 const float* __restrict__ W1,
                                                 __half* __restrict__ w1t,
                                                 const float* __restrict__ W2,
                                                 __half* __restrict__ w2t) {
    __shared__ int s[256];
    int b = blockIdx.x;
    int t = threadIdx.x;
    if (b < NB) {
        int v0 = blockhist[(size_t)(2 * t) * MAXB + b];
        int v1 = blockhist[(size_t)(2 * t + 1) * MAXB + b];
        int sum = v0 + v1;
        s[t] = sum;
        __syncthreads();
        for (int d = 1; d < 256; d <<= 1) {
            int val = (t >= d) ? s[t - d] : 0;
            __syncthreads();
            s[t] += val;
            __syncthreads();
        }
        int run = s[t] - sum;   // exclusive over pairs
        blockhist[(size_t)(2 * t) * MAXB + b] = run;
        blockhist[(size_t)(2 * t + 1) * MAXB + b] = run + v0;
        if (t == 255) gbhist[b] = s[255];
    } else if (b < NB + 4) {
        int idx = (b - NB) * 256 + t;       // 4 blocks cover 1024 ints
        if (idx < DBINS)            deghist[idx] = 0;
        else if (idx < 2 * DBINS)   dcur[idx - DBINS] = 0;
    } else if (b < NB + 36) {
        int i = (b - NB - 4) * 256 + t;     // 8192 elems: w1t[n][k] = W1[k][n]
        int n = i >> 7, k = i & 127;
        w1t[i] = __float2half(W1[k * NHID + n]);
    } else {
        int i = (b - NB - 36) * 256 + t;    // 8192 elems: w2t[n][k] = W2[k][n]
        int n = i >> 6, k = i & 63;
        w2t[i] = __float2half(W2[k * NFEAT + n]);
    }
}

// pass 3: partition edges into staging. Each block re-derives the boff scan
// from gbhist in LDS (fused bscan); block 0 publishes boff and off[N]=E.
__global__ __launch_bounds__(256) void k_partition(const int* __restrict__ ei, long long E,
                                                   long long perblk,
                                                   const int* __restrict__ gbhist,
                                                   const int* __restrict__ blockhist,
                                                   unsigned* __restrict__ staging, int NB,
                                                   int* __restrict__ boff,
                                                   int* __restrict__ offN) {
    __shared__ int smem[1024];
    __shared__ int s[256];
    int is64 = block_is64(ei, smem);
    int t = threadIdx.x;
    int v[4]; int sum = 0;
#pragma unroll
    for (int j = 0; j < 4; ++j) {
        int i = t * 4 + j;
        v[j] = (i < NB) ? gbhist[i] : 0;
        sum += v[j];
    }
    s[t] = sum;
    __syncthreads();
    for (int d = 1; d < 256; d <<= 1) {
        int val = (t >= d) ? s[t - d] : 0;
        __syncthreads();
        s[t] += val;
        __syncthreads();
    }
    int run = s[t] - sum;   // exclusive
    int* cur = smem;
    const int* bh = blockhist + (size_t)blockIdx.x * MAXB;
    bool b0 = (blockIdx.x == 0);
#pragma unroll
    for (int j = 0; j < 4; ++j) {
        int i = t * 4 + j;
        if (i < NB) cur[i] = run + bh[i];
        if (b0 && i <= NB) boff[i] = run;
        run += v[j];
    }
    if (b0 && t == 255) *offN = s[255];   // off[N] = E
    __syncthreads();
    long long lo = (long long)blockIdx.x * perblk;
    long long hi = lo + perblk; if (hi > E) hi = E;
    if (lo < hi) {
        for (long long e0 = lo + (long long)threadIdx.x * 8; e0 + 8 <= hi; e0 += 256 * 8) {
            int sv[8], d[8];
            load8(ei, is64, E, e0, 0, sv);
            load8(ei, is64, E, e0, 1, d);
#pragma unroll
            for (int j = 0; j < 8; ++j) {
                int pos = atomicAdd(&cur[d[j] >> BSHIFT], 1);
                staging[pos] = (unsigned)sv[j] | ((unsigned)(d[j] & (BNODES - 1)) << 24);
            }
        }
        long long tail = lo + ((hi - lo) & ~7LL);
        for (long long e = tail + threadIdx.x; e < hi; e += 256) {
            int sv = edge_idx(ei, is64, E, e, 0);
            int d = edge_idx(ei, is64, E, e, 1);
            int pos = atomicAdd(&cur[d >> BSHIFT], 1);
            staging[pos] = (unsigned)sv | ((unsigned)(d & (BNODES - 1)) << 24);
        }
    }
}

// pass 4: per-bucket CSR + dinv + degree histogram
__global__ __launch_bounds__(256) void k_bucket(const unsigned* __restrict__ staging,
                                                const int* __restrict__ boff,
                                                int N, int NB,
                                                int* __restrict__ off,
                                                int* __restrict__ esrc,
                                                float* __restrict__ dinv,
                                                int* __restrict__ deghist) {
    __shared__ int cnt_s[BNODES];
    __shared__ int scan_s[BNODES];
    __shared__ int dh[DBINS];
    int t = threadIdx.x;
    for (int b = blockIdx.x; b < NB; b += gridDim.x) {
        int base = b << BSHIFT;
        cnt_s[t] = 0;
        dh[t] = 0; dh[t + 256] = 0;
        __syncthreads();
        int lo = boff[b], hi = boff[b + 1];
        for (int e = lo + t; e < hi; e += 256)
            atomicAdd(&cnt_s[staging[e] >> 24], 1);
        __syncthreads();
        int v = cnt_s[t];
        scan_s[t] = v;
        __syncthreads();
        for (int d = 1; d < 256; d <<= 1) {
            int val = (t >= d) ? scan_s[t - d] : 0;
            __syncthreads();
            scan_s[t] += val;
            __syncthreads();
        }
        int excl = scan_s[t] - v;
        int node = base + t;
        if (node < N) {
            off[node] = lo + excl;
            dinv[node] = rsqrtf((float)v + 1.0f);   // +1 self loop
            atomicAdd(&dh[v < (DBINS - 1) ? v : (DBINS - 1)], 1);
        }
        __syncthreads();
        if (dh[t])       atomicAdd(&deghist[t], dh[t]);
        if (dh[t + 256]) atomicAdd(&deghist[t + 256], dh[t + 256]);
        cnt_s[t] = lo + excl;   // cursor
        __syncthreads();
        for (int e = lo + t; e < hi; e += 256) {
            unsigned sd = staging[e];
            int pos = atomicAdd(&cnt_s[sd >> 24], 1);
            esrc[pos] = (int)(sd & 0xFFFFFFu);
        }
        __syncthreads();
    }
}

// pass 5: degree-sorted perm scatter; deghist scan fused in (each block scans
// locally; global dcur holds running counts only, zeroed by k_colscan).
__global__ __launch_bounds__(256) void k_dperm(const int* __restrict__ off,
                                               const int* __restrict__ deghist,
                                               int* __restrict__ dcur,
                                               int* __restrict__ perm, int N) {
    __shared__ int dbase[DBINS];
    __shared__ int cnt[DBINS];
    __shared__ int base[DBINS];
    __shared__ int s[256];
    int t = threadIdx.x;
    int v0 = deghist[2 * t], v1 = deghist[2 * t + 1];
    int sum = v0 + v1;
    s[t] = sum;
    cnt[t] = 0; cnt[t + 256] = 0;
    __syncthreads();
    for (int d = 1; d < 256; d <<= 1) {
        int val = (t >= d) ? s[t - d] : 0;
        __syncthreads();
        s[t] += val;
        __syncthreads();
    }
    int run = s[t] - sum;
    dbase[2 * t] = run;
    dbase[2 * t + 1] = run + v0;
    __syncthreads();
    int n = blockIdx.x * 256 + t;
    int b = 0, myidx = 0;
    if (n < N) {
        int deg = off[n + 1] - off[n];
        b = deg < (DBINS - 1) ? deg : (DBINS - 1);
        myidx = atomicAdd(&cnt[b], 1);
    }
    __syncthreads();
    int c0 = cnt[t];       if (c0) base[t] = dbase[t] + atomicAdd(&dcur[t], c0);
    int c1 = cnt[t + 256]; if (c1) base[t + 256] = dbase[t + 256] + atomicAdd(&dcur[t + 256], c1);
    __syncthreads();
    if (n < N) perm[base[b] + myidx] = n;
}

// ---------- LDS XOR-swizzles ----------
__device__ __forceinline__ int swz(int row, int byteoff) {      // 256 B row stride
    return (row << 8) + (byteoff ^ ((row & 7) << 4));
}
__device__ __forceinline__ int swz64(int row, int byteoff) {    // 128 B row stride
    return (row << 7) + (byteoff ^ ((row & 7) << 4));
}

// ---------- GEMM1 (MFMA): x[N,128]fp32 @ W1t -> dinv[row]*out, fp16 xw1s[N,64] ----------
__global__ __launch_bounds__(256) void k_gemm1(const float* __restrict__ x,
                                               const __half* __restrict__ w1t,
                                               const float* __restrict__ dinv,
                                               __half* __restrict__ xw1s, int N) {
    __shared__ __align__(16) __half xs[64 * NFEAT];  // 16 KB, swizzled
    __shared__ __align__(16) __half ws[NHID * NFEAT]; // 16 KB, swizzled
    int t = threadIdx.x;
    // stage w1t [64][128] fp16 (vectorized, conflict-free)
    for (int i = t; i < NHID * NFEAT / 8; i += 256) {
        int row = i >> 4, c16 = (i & 15) << 4;
        uint4 v = ((const uint4*)w1t)[i];
        *(uint4*)((char*)ws + swz(row, c16)) = v;
    }
    int row0 = blockIdx.x * 64;
    for (int i = t; i < 64 * 32; i += 256) {
        int r = i >> 5, c4 = i & 31;
        int row = row0 + r;
        float4 v = (row < N) ? ((const float4*)x)[(size_t)row * 32 + c4]
                             : make_float4(0.f, 0.f, 0.f, 0.f);
        __half2 h0 = __floats2half2_rn(v.x, v.y);
        __half2 h1 = __floats2half2_rn(v.z, v.w);
        uint2 p = make_uint2(*(unsigned*)&h0, *(unsigned*)&h1);
        *(uint2*)((char*)xs + swz(r, c4 * 8)) = p;
    }
    __syncthreads();
    int wave = t >> 6, lane = t & 63;
    int lr = lane & 15, g = lane >> 4;
    int xrow = wave * 16 + lr;
    f16x8 xb[4];
#pragma unroll
    for (int kc = 0; kc < 4; ++kc)
        xb[kc] = *(const f16x8*)((const char*)xs + swz(xrow, kc * 64 + g * 16));
    int row = row0 + xrow;
    float di = (row < N) ? dinv[row] : 0.f;
#pragma unroll
    for (int c = 0; c < 4; ++c) {
        f32x4 acc = {0.f, 0.f, 0.f, 0.f};
#pragma unroll
        for (int kc = 0; kc < 4; ++kc) {
            f16x8 a = *(const f16x8*)((const char*)ws + swz(c * 16 + lr, kc * 64 + g * 16));
            acc = __builtin_amdgcn_mfma_f32_16x16x32_f16(a, xb[kc], acc, 0, 0, 0);
        }
        if (row < N) {
            __half2 o0 = __floats2half2_rn(di * acc[0], di * acc[1]);
            __half2 o1 = __floats2half2_rn(di * acc[2], di * acc[3]);
            uint2 p = make_uint2(*(unsigned*)&o0, *(unsigned*)&o1);
            *(uint2*)&xw1s[(size_t)row * NHID + c * 16 + g * 4] = p;
        }
    }
}

// ---------- group-per-node gather (reduction-free, 16 rows in flight) ----------
__device__ __forceinline__ void addhalf8(float2 (&acc)[4], uint4 p) {
    const __half2* hh = (const __half2*)&p;
#pragma unroll
    for (int j = 0; j < 4; ++j) {
        float2 v = __half22float2(hh[j]);
        acc[j].x += v.x; acc[j].y += v.y;
    }
}

// 8-lane group owns node d; lane li accumulates 16B slice li. Main loop keeps
// 16 independent row-loads in flight per lane (statically-indexed reg array).
__device__ __forceinline__ void gather_group(const int* __restrict__ off,
                                             const int* __restrict__ esrc,
                                             const uint4* __restrict__ feat4,
                                             int d, int li, int lo, int hi,
                                             float2 (&acc)[4]) {
#pragma unroll
    for (int j = 0; j < 4; ++j) acc[j] = make_float2(0.f, 0.f);
    int idx0 = (lo + li < hi) ? esrc[lo + li] : 0;       // prefetched chunk 0
    int idx1 = (lo + 8 + li < hi) ? esrc[lo + 8 + li] : 0; // prefetched chunk 1
    int e = lo;
    for (; e + 16 <= hi; ) {
        int cur0 = idx0, cur1 = idx1;
        int ne = e + 16;
        idx0 = (ne + li < hi) ? esrc[ne + li] : 0;       // prefetch next pair
        idx1 = (ne + 8 + li < hi) ? esrc[ne + 8 + li] : 0;
        uint4 p[16];
#pragma unroll
        for (int j = 0; j < 8; ++j) {
            int s = __shfl(cur0, j, 8);
            p[j] = feat4[(size_t)s * 8 + li];
        }
#pragma unroll
        for (int j = 0; j < 8; ++j) {
            int s = __shfl(cur1, j, 8);
            p[8 + j] = feat4[(size_t)s * 8 + li];
        }
#pragma unroll
        for (int j = 0; j < 16; ++j) addhalf8(acc, p[j]);
        e = ne;
    }
    int rem = hi - e;                 // 0..15; idx0/idx1 cover e..e+15
    int cur0 = idx0;
    if (rem >= 8) {
        uint4 p[8];
#pragma unroll
        for (int j = 0; j < 8; ++j) {
            int s = __shfl(cur0, j, 8);
            p[j] = feat4[(size_t)s * 8 + li];
        }
#pragma unroll
        for (int j = 0; j < 8; ++j) addhalf8(acc, p[j]);
        rem -= 8;
        cur0 = idx1;
    }
    for (int j = 0; j < rem; ++j) {   // rem < 8
        int s = __shfl(cur0, j, 8);
        addhalf8(acc, feat4[(size_t)s * 8 + li]);
    }
    addhalf8(acc, feat4[(size_t)d * 8 + li]);   // self loop (pre-scaled input)
}

// ---------- layer-1 aggregation: bias+relu, output pre-scaled fp16 h ----------
__global__ __launch_bounds__(256) void k_agg1(const int* __restrict__ off,
                                              const int* __restrict__ esrc,
                                              const int* __restrict__ perm,
                                              const float* __restrict__ dinv,
                                              const uint4* __restrict__ xw1s4,
                                              const float* __restrict__ b1,
                                              uint4* __restrict__ h4, int N) {
    int t = threadIdx.x;
    int lane = t & 63, wave = t >> 6;
    int g = lane >> 3, li = lane & 7;
    int slot = blockIdx.x * 32 + wave * 8 + g;
    bool valid = slot < N;
    int d  = valid ? perm[slot] : 0;
    int lo = valid ? off[d] : 0;
    int hi = valid ? off[d + 1] : 0;
    float2 acc[4];
    gather_group(off, esrc, xw1s4, d, li, lo, hi, acc);
    float dd = dinv[d];
    float4 bA = ((const float4*)b1)[li * 2 + 0];
    float4 bB = ((const float4*)b1)[li * 2 + 1];
    float v0 = fmaxf(dd * acc[0].x + bA.x, 0.f);
    float v1 = fmaxf(dd * acc[0].y + bA.y, 0.f);
    float v2 = fmaxf(dd * acc[1].x + bA.z, 0.f);
    float v3 = fmaxf(dd * acc[1].y + bA.w, 0.f);
    float v4 = fmaxf(dd * acc[2].x + bB.x, 0.f);
    float v5 = fmaxf(dd * acc[2].y + bB.y, 0.f);
    float v6 = fmaxf(dd * acc[3].x + bB.z, 0.f);
    float v7 = fmaxf(dd * acc[3].y + bB.w, 0.f);
    __half2 o[4];
    o[0] = __floats2half2_rn(dd * v0, dd * v1);   // pre-scaled for layer 2
    o[1] = __floats2half2_rn(dd * v2, dd * v3);
    o[2] = __floats2half2_rn(dd * v4, dd * v5);
    o[3] = __floats2half2_rn(dd * v6, dd * v7);
    if (valid) h4[(size_t)d * 8 + li] = *(const uint4*)o;
}

// ---------- layer-2 aggregation + GEMM2 fused (512 threads, 64 nodes/block) ----------
__global__ __launch_bounds__(512) void k_agg2g2(const int* __restrict__ off,
                                                const int* __restrict__ esrc,
                                                const int* __restrict__ perm,
                                                const float* __restrict__ dinv,
                                                const uint4* __restrict__ h4,
                                                const __half* __restrict__ w2t,
                                                const float* __restrict__ b2,
                                                float* __restrict__ out, int N) {
    __shared__ __align__(16) __half sB[NFEAT * NHID]; // w2t 128x64 fp16, 16 KB swz
    __shared__ __align__(16) __half sH[64 * NHID];    // hi tile 64x64, 8 KB swz
    __shared__ __align__(16) __half sL[64 * NHID];    // lo tile 64x64, 8 KB swz
    __shared__ int nid[64];
    int t = threadIdx.x;
    // stage w2t [128][64] fp16 (vectorized, conflict-free)
    for (int i = t; i < NFEAT * NHID / 8; i += 512) {
        int row = i >> 3, c16 = (i & 7) << 4;
        uint4 v = ((const uint4*)w2t)[i];
        *(uint4*)((char*)sB + swz64(row, c16)) = v;
    }
    int lane = t & 63, wave = t >> 6;
    int g = lane >> 3, li = lane & 7;
    int gi = wave * 8 + g;                 // group index 0..63 = LDS tile row
    int slot = blockIdx.x * 64 + gi;
    bool valid = slot < N;
    int d  = valid ? perm[slot] : 0;
    int lo = valid ? off[d] : 0;
    int hi = valid ? off[d + 1] : 0;
    float2 acc[4];
    gather_group(off, esrc, h4, d, li, lo, hi, acc);
    float dd = dinv[d];
    float v[8] = {dd * acc[0].x, dd * acc[0].y, dd * acc[1].x, dd * acc[1].y,
                  dd * acc[2].x, dd * acc[2].y, dd * acc[3].x, dd * acc[3].y};
    __half hh[8], ll[8];
#pragma unroll
    for (int j = 0; j < 8; ++j) {
        hh[j] = __float2half(v[j]);
        ll[j] = __float2half(v[j] - __half2float(hh[j]));
    }
    uint4 ph, pl;
    __half2* hp = (__half2*)&ph;
    __half2* lp = (__half2*)&pl;
#pragma unroll
    for (int j = 0; j < 4; ++j) {
        hp[j] = __halves2half2(hh[2 * j], hh[2 * j + 1]);
        lp[j] = __halves2half2(ll[2 * j], ll[2 * j + 1]);
    }
    *(uint4*)((char*)sH + swz64(gi, li * 16)) = ph;
    *(uint4*)((char*)sL + swz64(gi, li * 16)) = pl;
    if (li == 0) nid[gi] = valid ? d : -1;
    __syncthreads();
    // MFMA epilogue: 8 waves -> (4 row-tiles x 2 col-halves)
    int lr = lane & 15, g2 = lane >> 4;
    int rtile = wave & 3, chalf = wave >> 2;
    int xrow = rtile * 16 + lr;
    int node = nid[xrow];
    f16x8 xh[2], xl[2];
#pragma unroll
    for (int kc = 0; kc < 2; ++kc) {
        xh[kc] = *(const f16x8*)((const char*)sH + swz64(xrow, kc * 64 + g2 * 16));
        xl[kc] = *(const f16x8*)((const char*)sL + swz64(xrow, kc * 64 + g2 * 16));
    }
#pragma unroll
    for (int ci = 0; ci < 4; ++ci) {
        int c = chalf * 4 + ci;
        f32x4 a2 = {0.f, 0.f, 0.f, 0.f};
#pragma unroll
        for (int kc = 0; kc < 2; ++kc) {
            f16x8 a = *(const f16x8*)((const char*)sB + swz64(c * 16 + lr, kc * 64 + g2 * 16));
            a2 = __builtin_amdgcn_mfma_f32_16x16x32_f16(a, xl[kc], a2, 0, 0, 0);
            a2 = __builtin_amdgcn_mfma_f32_16x16x32_f16(a, xh[kc], a2, 0, 0, 0);
        }
        if (node >= 0) {
            float4 bb = *(const float4*)&b2[c * 16 + g2 * 4];
            float4 o = make_float4(a2[0] + bb.x, a2[1] + bb.y,
                                   a2[2] + bb.z, a2[3] + bb.w);
            *(float4*)&out[(size_t)node * NFEAT + c * 16 + g2 * 4] = o;
        }
    }
}

static inline char* align256(char* p) {
    return (char*)(((uintptr_t)p + 255) & ~(uintptr_t)255);
}

extern "C" void kernel_launch(void* const* d_in, const int* in_sizes, int n_in,
                              void* d_out, int out_size, void* d_ws, size_t ws_size,
                              hipStream_t stream) {
    const float* x  = (const float*)d_in[0];
    const int*   ei = (const int*)d_in[1];
    const float* W1 = (const float*)d_in[2];
    const float* b1 = (const float*)d_in[3];
    const float* W2 = (const float*)d_in[4];
    const float* b2 = (const float*)d_in[5];
    float* out = (float*)d_out;

    const int N = in_sizes[0] / NFEAT;            // 100000
    const long long E = in_sizes[1] / 2;          // 1600000
    const int NB = (N + BNODES - 1) >> BSHIFT;    // 391 buckets

    // workspace layout
    char* w = (char*)d_ws;
    int*      gbhist    = (int*)w;                        // MAXB
    int*      boff      = gbhist + MAXB;                  // MAXB+1
    int*      deghist   = boff + MAXB + 1;                // DBINS
    int*      dcur      = deghist + DBINS;                // DBINS
    int*      blockhist = dcur + DBINS;                   // PBLK*MAXB (2 MB)
    float*    dinv      = (float*)(blockhist + (size_t)PBLK * MAXB);  // N
    int*      off       = (int*)(dinv + N);               // N+1
    int*      perm      = off + N + 1;                    // N
    char*     p         = align256((char*)(perm + N));
    unsigned* staging   = (unsigned*)p;                   // E * 4 B
    p = align256((char*)(staging + E));
    int*      esrc      = (int*)p;                        // E
    p = align256((char*)(esrc + E));
    __half*   xw1s      = (__half*)p;                     // N*64 fp16
    p = align256((char*)(xw1s + (size_t)N * NHID));
    __half*   h         = (__half*)p;                     // N*64 fp16
    p = align256((char*)(h + (size_t)N * NHID));
    __half*   w1t       = (__half*)p;                     // 64*128 fp16
    p = align256((char*)(w1t + NFEAT * NHID));
    __half*   w2t       = (__half*)p;                     // 128*64 fp16

    long long perblk = ((E + PBLK - 1) / PBLK + 7) & ~7LL;   // multiple of 8

    k_hist<<<PBLK, 256, 0, stream>>>(ei, E, perblk, blockhist, NB);
    k_colscan<<<NB + 68, 256, 0, stream>>>(blockhist, gbhist, deghist, dcur, NB,
                                           W1, w1t, W2, w2t);
    k_partition<<<PBLK, 256, 0, stream>>>(ei, E, perblk, gbhist, blockhist, staging,
                                          NB, boff, off + N);
    k_bucket<<<NB, 256, 0, stream>>>(staging, boff, N, NB, off, esrc, dinv, deghist);
    k_dperm<<<(N + 255) / 256, 256, 0, stream>>>(off, deghist, dcur, perm, N);

    k_gemm1<<<(N + 63) / 64, 256, 0, stream>>>(x, w1t, dinv, xw1s, N);

    k_agg1<<<(N + 31) / 32, 256, 0, stream>>>(off, esrc, perm, dinv, (const uint4*)xw1s,
                                              b1, (uint4*)h, N);
    k_agg2g2<<<(N + 63) / 64, 512, 0, stream>>>(off, esrc, perm, dinv, (const uint4*)h,
                                                w2t, b2, out, N);
}

// Round 12
// 248.417 us; speedup vs baseline: 1.0295x; 1.0295x over previous
//
#include <hip/hip_runtime.h>
#include <hip/hip_fp16.h>

#define NFEAT 128
#define NHID 64
#define MAXB 1024          // max dst buckets (node>>8), supports N<=262144
#define BSHIFT 8
#define BNODES 256
#define PBLK 512           // edge-pass grid (blocks)
#define DBINS 512          // degree bins for counting sort

typedef _Float16 f16x8 __attribute__((ext_vector_type(8)));
typedef float f32x4 __attribute__((ext_vector_type(4)));

// ================= preprocessing =================

__device__ __forceinline__ int edge_idx(const int* __restrict__ ei, int is64,
                                        long long E, long long e, int which) {
    long long pos = which ? (E + e) : e;
    return is64 ? ei[2 * pos] : ei[pos];
}

__device__ __forceinline__ void load8(const int* __restrict__ ei, int is64,
                                      long long E, long long e0, int which,
                                      int (&v)[8]) {
    if (is64) {
        const int* base = ei + 2 * (which ? E + e0 : e0);
        int4 a = *(const int4*)(base + 0);
        int4 b = *(const int4*)(base + 4);
        int4 c = *(const int4*)(base + 8);
        int4 d = *(const int4*)(base + 12);
        v[0] = a.x; v[1] = a.z; v[2] = b.x; v[3] = b.z;
        v[4] = c.x; v[5] = c.z; v[6] = d.x; v[7] = d.z;
    } else {
        const int* base = ei + (which ? E + e0 : e0);
        int4 a = *(const int4*)(base + 0);
        int4 b = *(const int4*)(base + 4);
        v[0] = a.x; v[1] = a.y; v[2] = a.z; v[3] = a.w;
        v[4] = b.x; v[5] = b.y; v[6] = b.z; v[7] = b.w;
    }
}

// per-block int64 detection: odd int32 words of first 4096 words all zero => int64
__device__ __forceinline__ int block_is64(const int* __restrict__ ei, int* smem) {
    if (threadIdx.x == 0) smem[0] = 0;
    __syncthreads();
    int acc = 0;
    for (int i = 1 + 2 * (int)threadIdx.x; i < 4096; i += 512)
        acc |= ei[i];
    atomicOr(&smem[0], acc);
    __syncthreads();
    int r = (smem[0] == 0) ? 1 : 0;
    __syncthreads();
    return r;
}

// pass 1: per-block bucket histogram -> blockhist (no global atomics)
__global__ __launch_bounds__(256) void k_hist(const int* __restrict__ ei, long long E,
                                              long long perblk,
                                              int* __restrict__ blockhist, int NB) {
    __shared__ int smem[1024];
    int is64 = block_is64(ei, smem);
    int* hist = smem;
    for (int i = threadIdx.x; i < NB; i += 256) hist[i] = 0;
    __syncthreads();
    long long lo = (long long)blockIdx.x * perblk;
    long long hi = lo + perblk; if (hi > E) hi = E;
    if (lo < hi) {
        for (long long e0 = lo + (long long)threadIdx.x * 8; e0 + 8 <= hi; e0 += 256 * 8) {
            int d[8];
            load8(ei, is64, E, e0, 1, d);
#pragma unroll
            for (int j = 0; j < 8; ++j)
                atomicAdd(&hist[d[j] >> BSHIFT], 1);
        }
        long long tail = lo + ((hi - lo) & ~7LL);
        for (long long e = tail + threadIdx.x; e < hi; e += 256) {
            int d = edge_idx(ei, is64, E, e, 1);
            atomicAdd(&hist[d >> BSHIFT], 1);
        }
    }
    __syncthreads();
    int* bh = blockhist + (size_t)blockIdx.x * MAXB;
    for (int i = threadIdx.x; i < NB; i += 256) bh[i] = hist[i];
}

// pass 2: block b<NB scans blockhist column b in place -> exclusive per-block
// offsets; total -> gbhist[b]. Blocks b>=NB zero deghist/dcur and convert
// W1/W2 fp32 -> transposed fp16 (w1t[64][128], w2t[128][64]) -- free work
// folded into an existing dispatch.
__global__ __launch_bounds__(256) void k_colscan(int* __restrict__ blockhist,
                                                 int* __restrict__ gbhist,
                                                 int* __restrict__ deghist,
                                                 int* __restrict__ dcur, int NB,
                                                 const float* __restrict__ W1,
                                                 __half* __restrict__ w1t,
                                                 const float* __restrict__ W2,
                                                 __half* __restrict__ w2t) {
    __shared__ int s[256];
    int b = blockIdx.x;
    int t = threadIdx.x;
    if (b < NB) {
        int v0 = blockhist[(size_t)(2 * t) * MAXB + b];
        int v1 = blockhist[(size_t)(2 * t + 1) * MAXB + b];
        int sum = v0 + v1;
        s[t] = sum;
        __syncthreads();
        for (int d = 1; d < 256; d <<= 1) {
            int val = (t >= d) ? s[t - d] : 0;
            __syncthreads();
            s[t] += val;
            __syncthreads();
        }
        int run = s[t] - sum;   // exclusive over pairs
        blockhist[(size_t)(2 * t) * MAXB + b] = run;
        blockhist[(size_t)(2 * t + 1) * MAXB + b] = run + v0;
        if (t == 255) gbhist[b] = s[255];
    } else if (b < NB + 4) {
        int idx = (b - NB) * 256 + t;       // 4 blocks cover 1024 ints
        if (idx < DBINS)            deghist[idx] = 0;
        else if (idx < 2 * DBINS)   dcur[idx - DBINS] = 0;
    } else if (b < NB + 36) {
        int i = (b - NB - 4) * 256 + t;     // 8192 elems: w1t[n][k] = W1[k][n]
        int n = i >> 7, k = i & 127;
        w1t[i] = __float2half(W1[k * NHID + n]);
    } else {
        int i = (b - NB - 36) * 256 + t;    // 8192 elems: w2t[n][k] = W2[k][n]
        int n = i >> 6, k = i & 63;
        w2t[i] = __float2half(W2[k * NFEAT + n]);
    }
}

// pass 3: partition edges into staging. Each block re-derives the boff scan
// from gbhist in LDS (fused bscan); block 0 publishes boff and off[N]=E.
__global__ __launch_bounds__(256) void k_partition(const int* __restrict__ ei, long long E,
                                                   long long perblk,
                                                   const int* __restrict__ gbhist,
                                                   const int* __restrict__ blockhist,
                                                   unsigned* __restrict__ staging, int NB,
                                                   int* __restrict__ boff,
                                                   int* __restrict__ offN) {
    __shared__ int smem[1024];
    __shared__ int s[256];
    int is64 = block_is64(ei, smem);
    int t = threadIdx.x;
    int v[4]; int sum = 0;
#pragma unroll
    for (int j = 0; j < 4; ++j) {
        int i = t * 4 + j;
        v[j] = (i < NB) ? gbhist[i] : 0;
        sum += v[j];
    }
    s[t] = sum;
    __syncthreads();
    for (int d = 1; d < 256; d <<= 1) {
        int val = (t >= d) ? s[t - d] : 0;
        __syncthreads();
        s[t] += val;
        __syncthreads();
    }
    int run = s[t] - sum;   // exclusive
    int* cur = smem;
    const int* bh = blockhist + (size_t)blockIdx.x * MAXB;
    bool b0 = (blockIdx.x == 0);
#pragma unroll
    for (int j = 0; j < 4; ++j) {
        int i = t * 4 + j;
        if (i < NB) cur[i] = run + bh[i];
        if (b0 && i <= NB) boff[i] = run;
        run += v[j];
    }
    if (b0 && t == 255) *offN = s[255];   // off[N] = E
    __syncthreads();
    long long lo = (long long)blockIdx.x * perblk;
    long long hi = lo + perblk; if (hi > E) hi = E;
    if (lo < hi) {
        for (long long e0 = lo + (long long)threadIdx.x * 8; e0 + 8 <= hi; e0 += 256 * 8) {
            int sv[8], d[8];
            load8(ei, is64, E, e0, 0, sv);
            load8(ei, is64, E, e0, 1, d);
#pragma unroll
            for (int j = 0; j < 8; ++j) {
                int pos = atomicAdd(&cur[d[j] >> BSHIFT], 1);
                staging[pos] = (unsigned)sv[j] | ((unsigned)(d[j] & (BNODES - 1)) << 24);
            }
        }
        long long tail = lo + ((hi - lo) & ~7LL);
        for (long long e = tail + threadIdx.x; e < hi; e += 256) {
            int sv = edge_idx(ei, is64, E, e, 0);
            int d = edge_idx(ei, is64, E, e, 1);
            int pos = atomicAdd(&cur[d >> BSHIFT], 1);
            staging[pos] = (unsigned)sv | ((unsigned)(d & (BNODES - 1)) << 24);
        }
    }
}

// pass 4: per-bucket CSR + dinv + degree histogram
__global__ __launch_bounds__(256) void k_bucket(const unsigned* __restrict__ staging,
                                                const int* __restrict__ boff,
                                                int N, int NB,
                                                int* __restrict__ off,
                                                int* __restrict__ esrc,
                                                float* __restrict__ dinv,
                                                int* __restrict__ deghist) {
    __shared__ int cnt_s[BNODES];
    __shared__ int scan_s[BNODES];
    __shared__ int dh[DBINS];
    int t = threadIdx.x;
    for (int b = blockIdx.x; b < NB; b += gridDim.x) {
        int base = b << BSHIFT;
        cnt_s[t] = 0;
        dh[t] = 0; dh[t + 256] = 0;
        __syncthreads();
        int lo = boff[b], hi = boff[b + 1];
        for (int e = lo + t; e < hi; e += 256)
            atomicAdd(&cnt_s[staging[e] >> 24], 1);
        __syncthreads();
        int v = cnt_s[t];
        scan_s[t] = v;
        __syncthreads();
        for (int d = 1; d < 256; d <<= 1) {
            int val = (t >= d) ? scan_s[t - d] : 0;
            __syncthreads();
            scan_s[t] += val;
            __syncthreads();
        }
        int excl = scan_s[t] - v;
        int node = base + t;
        if (node < N) {
            off[node] = lo + excl;
            dinv[node] = rsqrtf((float)v + 1.0f);   // +1 self loop
            atomicAdd(&dh[v < (DBINS - 1) ? v : (DBINS - 1)], 1);
        }
        __syncthreads();
        if (dh[t])       atomicAdd(&deghist[t], dh[t]);
        if (dh[t + 256]) atomicAdd(&deghist[t + 256], dh[t + 256]);
        cnt_s[t] = lo + excl;   // cursor
        __syncthreads();
        for (int e = lo + t; e < hi; e += 256) {
            unsigned sd = staging[e];
            int pos = atomicAdd(&cnt_s[sd >> 24], 1);
            esrc[pos] = (int)(sd & 0xFFFFFFu);
        }
        __syncthreads();
    }
}

// pass 5: degree-sorted perm scatter; deghist scan fused in (each block scans
// locally; global dcur holds running counts only, zeroed by k_colscan).
__global__ __launch_bounds__(256) void k_dperm(const int* __restrict__ off,
                                               const int* __restrict__ deghist,
                                               int* __restrict__ dcur,
                                               int* __restrict__ perm, int N) {
    __shared__ int dbase[DBINS];
    __shared__ int cnt[DBINS];
    __shared__ int base[DBINS];
    __shared__ int s[256];
    int t = threadIdx.x;
    int v0 = deghist[2 * t], v1 = deghist[2 * t + 1];
    int sum = v0 + v1;
    s[t] = sum;
    cnt[t] = 0; cnt[t + 256] = 0;
    __syncthreads();
    for (int d = 1; d < 256; d <<= 1) {
        int val = (t >= d) ? s[t - d] : 0;
        __syncthreads();
        s[t] += val;
        __syncthreads();
    }
    int run = s[t] - sum;
    dbase[2 * t] = run;
    dbase[2 * t + 1] = run + v0;
    __syncthreads();
    int n = blockIdx.x * 256 + t;
    int b = 0, myidx = 0;
    if (n < N) {
        int deg = off[n + 1] - off[n];
        b = deg < (DBINS - 1) ? deg : (DBINS - 1);
        myidx = atomicAdd(&cnt[b], 1);
    }
    __syncthreads();
    int c0 = cnt[t];       if (c0) base[t] = dbase[t] + atomicAdd(&dcur[t], c0);
    int c1 = cnt[t + 256]; if (c1) base[t + 256] = dbase[t + 256] + atomicAdd(&dcur[t + 256], c1);
    __syncthreads();
    if (n < N) perm[base[b] + myidx] = n;
}

// ---------- LDS XOR-swizzles ----------
__device__ __forceinline__ int swz(int row, int byteoff) {      // 256 B row stride
    return (row << 8) + (byteoff ^ ((row & 7) << 4));
}
__device__ __forceinline__ int swz64(int row, int byteoff) {    // 128 B row stride
    return (row << 7) + (byteoff ^ ((row & 7) << 4));
}

// ---------- GEMM1 (MFMA): x[N,128]fp32 @ W1t -> dinv[row]*out, fp16 xw1s[N,64] ----------
__global__ __launch_bounds__(256) void k_gemm1(const float* __restrict__ x,
                                               const __half* __restrict__ w1t,
                                               const float* __restrict__ dinv,
                                               __half* __restrict__ xw1s, int N) {
    __shared__ __align__(16) __half xs[64 * NFEAT];  // 16 KB, swizzled
    __shared__ __align__(16) __half ws[NHID * NFEAT]; // 16 KB, swizzled
    int t = threadIdx.x;
    // stage w1t [64][128] fp16 (vectorized, conflict-free)
    for (int i = t; i < NHID * NFEAT / 8; i += 256) {
        int row = i >> 4, c16 = (i & 15) << 4;
        uint4 v = ((const uint4*)w1t)[i];
        *(uint4*)((char*)ws + swz(row, c16)) = v;
    }
    int row0 = blockIdx.x * 64;
    for (int i = t; i < 64 * 32; i += 256) {
        int r = i >> 5, c4 = i & 31;
        int row = row0 + r;
        float4 v = (row < N) ? ((const float4*)x)[(size_t)row * 32 + c4]
                             : make_float4(0.f, 0.f, 0.f, 0.f);
        __half2 h0 = __floats2half2_rn(v.x, v.y);
        __half2 h1 = __floats2half2_rn(v.z, v.w);
        uint2 p = make_uint2(*(unsigned*)&h0, *(unsigned*)&h1);
        *(uint2*)((char*)xs + swz(r, c4 * 8)) = p;
    }
    __syncthreads();
    int wave = t >> 6, lane = t & 63;
    int lr = lane & 15, g = lane >> 4;
    int xrow = wave * 16 + lr;
    f16x8 xb[4];
#pragma unroll
    for (int kc = 0; kc < 4; ++kc)
        xb[kc] = *(const f16x8*)((const char*)xs + swz(xrow, kc * 64 + g * 16));
    int row = row0 + xrow;
    float di = (row < N) ? dinv[row] : 0.f;
#pragma unroll
    for (int c = 0; c < 4; ++c) {
        f32x4 acc = {0.f, 0.f, 0.f, 0.f};
#pragma unroll
        for (int kc = 0; kc < 4; ++kc) {
            f16x8 a = *(const f16x8*)((const char*)ws + swz(c * 16 + lr, kc * 64 + g * 16));
            acc = __builtin_amdgcn_mfma_f32_16x16x32_f16(a, xb[kc], acc, 0, 0, 0);
        }
        if (row < N) {
            __half2 o0 = __floats2half2_rn(di * acc[0], di * acc[1]);
            __half2 o1 = __floats2half2_rn(di * acc[2], di * acc[3]);
            uint2 p = make_uint2(*(unsigned*)&o0, *(unsigned*)&o1);
            *(uint2*)&xw1s[(size_t)row * NHID + c * 16 + g * 4] = p;
        }
    }
}

// ---------- group-per-node gather (reduction-free, 8-wide; round-9 form) ----------
__device__ __forceinline__ void addhalf8(float2 (&acc)[4], uint4 p) {
    const __half2* hh = (const __half2*)&p;
#pragma unroll
    for (int j = 0; j < 4; ++j) {
        float2 v = __half22float2(hh[j]);
        acc[j].x += v.x; acc[j].y += v.y;
    }
}

// 8-lane group owns node d; lane li accumulates 16B slice li.
__device__ __forceinline__ void gather_group(const int* __restrict__ off,
                                             const int* __restrict__ esrc,
                                             const uint4* __restrict__ feat4,
                                             int d, int li, int lo, int hi,
                                             float2 (&acc)[4]) {
#pragma unroll
    for (int j = 0; j < 4; ++j) acc[j] = make_float2(0.f, 0.f);
    int idx = (lo + li < hi) ? esrc[lo + li] : 0;   // prefetched chunk
    for (int e = lo; e < hi; e += 8) {
        int nrem = hi - e;
        int cur = idx;
        int ne = e + 8;
        idx = (ne + li < hi) ? esrc[ne + li] : 0;   // prefetch next chunk
        if (nrem >= 8) {
#pragma unroll
            for (int j = 0; j < 8; ++j) {
                int s = __shfl(cur, j, 8);
                addhalf8(acc, feat4[(size_t)s * 8 + li]);
            }
        } else {
            for (int j = 0; j < nrem; ++j) {
                int s = __shfl(cur, j, 8);
                addhalf8(acc, feat4[(size_t)s * 8 + li]);
            }
        }
    }
    addhalf8(acc, feat4[(size_t)d * 8 + li]);   // self loop (pre-scaled input)
}

// ---------- layer-1 aggregation: bias+relu, output pre-scaled fp16 h ----------
__global__ __launch_bounds__(256) void k_agg1(const int* __restrict__ off,
                                              const int* __restrict__ esrc,
                                              const int* __restrict__ perm,
                                              const float* __restrict__ dinv,
                                              const uint4* __restrict__ xw1s4,
                                              const float* __restrict__ b1,
                                              uint4* __restrict__ h4, int N) {
    int t = threadIdx.x;
    int lane = t & 63, wave = t >> 6;
    int g = lane >> 3, li = lane & 7;
    int slot = blockIdx.x * 32 + wave * 8 + g;
    bool valid = slot < N;
    int d  = valid ? perm[slot] : 0;
    int lo = valid ? off[d] : 0;
    int hi = valid ? off[d + 1] : 0;
    float2 acc[4];
    gather_group(off, esrc, xw1s4, d, li, lo, hi, acc);
    float dd = dinv[d];
    float4 bA = ((const float4*)b1)[li * 2 + 0];
    float4 bB = ((const float4*)b1)[li * 2 + 1];
    float v0 = fmaxf(dd * acc[0].x + bA.x, 0.f);
    float v1 = fmaxf(dd * acc[0].y + bA.y, 0.f);
    float v2 = fmaxf(dd * acc[1].x + bA.z, 0.f);
    float v3 = fmaxf(dd * acc[1].y + bA.w, 0.f);
    float v4 = fmaxf(dd * acc[2].x + bB.x, 0.f);
    float v5 = fmaxf(dd * acc[2].y + bB.y, 0.f);
    float v6 = fmaxf(dd * acc[3].x + bB.z, 0.f);
    float v7 = fmaxf(dd * acc[3].y + bB.w, 0.f);
    __half2 o[4];
    o[0] = __floats2half2_rn(dd * v0, dd * v1);   // pre-scaled for layer 2
    o[1] = __floats2half2_rn(dd * v2, dd * v3);
    o[2] = __floats2half2_rn(dd * v4, dd * v5);
    o[3] = __floats2half2_rn(dd * v6, dd * v7);
    if (valid) h4[(size_t)d * 8 + li] = *(const uint4*)o;
}

// ---------- layer-2 aggregation + GEMM2 fused (512 threads, 64 nodes/block) ----------
__global__ __launch_bounds__(512) void k_agg2g2(const int* __restrict__ off,
                                                const int* __restrict__ esrc,
                                                const int* __restrict__ perm,
                                                const float* __restrict__ dinv,
                                                const uint4* __restrict__ h4,
                                                const __half* __restrict__ w2t,
                                                const float* __restrict__ b2,
                                                float* __restrict__ out, int N) {
    __shared__ __align__(16) __half sB[NFEAT * NHID]; // w2t 128x64 fp16, 16 KB swz
    __shared__ __align__(16) __half sH[64 * NHID];    // hi tile 64x64, 8 KB swz
    __shared__ __align__(16) __half sL[64 * NHID];    // lo tile 64x64, 8 KB swz
    __shared__ int nid[64];
    int t = threadIdx.x;
    // stage w2t [128][64] fp16 (vectorized, conflict-free)
    for (int i = t; i < NFEAT * NHID / 8; i += 512) {
        int row = i >> 3, c16 = (i & 7) << 4;
        uint4 v = ((const uint4*)w2t)[i];
        *(uint4*)((char*)sB + swz64(row, c16)) = v;
    }
    int lane = t & 63, wave = t >> 6;
    int g = lane >> 3, li = lane & 7;
    int gi = wave * 8 + g;                 // group index 0..63 = LDS tile row
    int slot = blockIdx.x * 64 + gi;
    bool valid = slot < N;
    int d  = valid ? perm[slot] : 0;
    int lo = valid ? off[d] : 0;
    int hi = valid ? off[d + 1] : 0;
    float2 acc[4];
    gather_group(off, esrc, h4, d, li, lo, hi, acc);
    float dd = dinv[d];
    float v[8] = {dd * acc[0].x, dd * acc[0].y, dd * acc[1].x, dd * acc[1].y,
                  dd * acc[2].x, dd * acc[2].y, dd * acc[3].x, dd * acc[3].y};
    __half hh[8], ll[8];
#pragma unroll
    for (int j = 0; j < 8; ++j) {
        hh[j] = __float2half(v[j]);
        ll[j] = __float2half(v[j] - __half2float(hh[j]));
    }
    uint4 ph, pl;
    __half2* hp = (__half2*)&ph;
    __half2* lp = (__half2*)&pl;
#pragma unroll
    for (int j = 0; j < 4; ++j) {
        hp[j] = __halves2half2(hh[2 * j], hh[2 * j + 1]);
        lp[j] = __halves2half2(ll[2 * j], ll[2 * j + 1]);
    }
    *(uint4*)((char*)sH + swz64(gi, li * 16)) = ph;
    *(uint4*)((char*)sL + swz64(gi, li * 16)) = pl;
    if (li == 0) nid[gi] = valid ? d : -1;
    __syncthreads();
    // MFMA epilogue: 8 waves -> (4 row-tiles x 2 col-halves)
    int lr = lane & 15, g2 = lane >> 4;
    int rtile = wave & 3, chalf = wave >> 2;
    int xrow = rtile * 16 + lr;
    int node = nid[xrow];
    f16x8 xh[2], xl[2];
#pragma unroll
    for (int kc = 0; kc < 2; ++kc) {
        xh[kc] = *(const f16x8*)((const char*)sH + swz64(xrow, kc * 64 + g2 * 16));
        xl[kc] = *(const f16x8*)((const char*)sL + swz64(xrow, kc * 64 + g2 * 16));
    }
#pragma unroll
    for (int ci = 0; ci < 4; ++ci) {
        int c = chalf * 4 + ci;
        f32x4 a2 = {0.f, 0.f, 0.f, 0.f};
#pragma unroll
        for (int kc = 0; kc < 2; ++kc) {
            f16x8 a = *(const f16x8*)((const char*)sB + swz64(c * 16 + lr, kc * 64 + g2 * 16));
            a2 = __builtin_amdgcn_mfma_f32_16x16x32_f16(a, xl[kc], a2, 0, 0, 0);
            a2 = __builtin_amdgcn_mfma_f32_16x16x32_f16(a, xh[kc], a2, 0, 0, 0);
        }
        if (node >= 0) {
            float4 bb = *(const float4*)&b2[c * 16 + g2 * 4];
            f32x4 o4;
            o4[0] = a2[0] + bb.x; o4[1] = a2[1] + bb.y;
            o4[2] = a2[2] + bb.z; o4[3] = a2[3] + bb.w;
            // nontemporal: out is a pure write stream, never re-read --
            // keep it from evicting the gather-hot h array in L2/L3.
            __builtin_nontemporal_store(o4, (f32x4*)&out[(size_t)node * NFEAT + c * 16 + g2 * 4]);
        }
    }
}

static inline char* align256(char* p) {
    return (char*)(((uintptr_t)p + 255) & ~(uintptr_t)255);
}

extern "C" void kernel_launch(void* const* d_in, const int* in_sizes, int n_in,
                              void* d_out, int out_size, void* d_ws, size_t ws_size,
                              hipStream_t stream) {
    const float* x  = (const float*)d_in[0];
    const int*   ei = (const int*)d_in[1];
    const float* W1 = (const float*)d_in[2];
    const float* b1 = (const float*)d_in[3];
    const float* W2 = (const float*)d_in[4];
    const float* b2 = (const float*)d_in[5];
    float* out = (float*)d_out;

    const int N = in_sizes[0] / NFEAT;            // 100000
    const long long E = in_sizes[1] / 2;          // 1600000
    const int NB = (N + BNODES - 1) >> BSHIFT;    // 391 buckets

    // workspace layout
    char* w = (char*)d_ws;
    int*      gbhist    = (int*)w;                        // MAXB
    int*      boff      = gbhist + MAXB;                  // MAXB+1
    int*      deghist   = boff + MAXB + 1;                // DBINS
    int*      dcur      = deghist + DBINS;                // DBINS
    int*      blockhist = dcur + DBINS;                   // PBLK*MAXB (2 MB)
    float*    dinv      = (float*)(blockhist + (size_t)PBLK * MAXB);  // N
    int*      off       = (int*)(dinv + N);               // N+1
    int*      perm      = off + N + 1;                    // N
    char*     p         = align256((char*)(perm + N));
    unsigned* staging   = (unsigned*)p;                   // E * 4 B
    p = align256((char*)(staging + E));
    int*      esrc      = (int*)p;                        // E
    p = align256((char*)(esrc + E));
    __half*   xw1s      = (__half*)p;                     // N*64 fp16
    p = align256((char*)(xw1s + (size_t)N * NHID));
    __half*   h         = (__half*)p;                     // N*64 fp16
    p = align256((char*)(h + (size_t)N * NHID));
    __half*   w1t       = (__half*)p;                     // 64*128 fp16
    p = align256((char*)(w1t + NFEAT * NHID));
    __half*   w2t       = (__half*)p;                     // 128*64 fp16

    long long perblk = ((E + PBLK - 1) / PBLK + 7) & ~7LL;   // multiple of 8

    k_hist<<<PBLK, 256, 0, stream>>>(ei, E, perblk, blockhist, NB);
    k_colscan<<<NB + 68, 256, 0, stream>>>(blockhist, gbhist, deghist, dcur, NB,
                                           W1, w1t, W2, w2t);
    k_partition<<<PBLK, 256, 0, stream>>>(ei, E, perblk, gbhist, blockhist, staging,
                                          NB, boff, off + N);
    k_bucket<<<NB, 256, 0, stream>>>(staging, boff, N, NB, off, esrc, dinv, deghist);
    k_dperm<<<(N + 255) / 256, 256, 0, stream>>>(off, deghist, dcur, perm, N);

    k_gemm1<<<(N + 63) / 64, 256, 0, stream>>>(x, w1t, dinv, xw1s, N);

    k_agg1<<<(N + 31) / 32, 256, 0, stream>>>(off, esrc, perm, dinv, (const uint4*)xw1s,
                                              b1, (uint4*)h, N);
    k_agg2g2<<<(N + 63) / 64, 512, 0, stream>>>(off, esrc, perm, dinv, (const uint4*)h,
                                                w2t, b2, out, N);
}